// Round 4
// baseline (547.490 us; speedup 1.0000x reference)
//
#include <hip/hip_runtime.h>
#include <stdint.h>

// HilbertSerialization: stable argsort of 26-bit Hilbert+batch keys.
// Onesweep-style: genkeys(+all 3 hists in one read) -> scan3 ->
// 3 x scatter with decoupled-lookback (single-word status protocol,
// relaxed agent-scope atomics). Scatter stages (val<<32|key) pairs into
// LDS in digit-sorted order so global writes are 64B-run contiguous.

#define THREADS 256
#define TILE 4096                 // elements per block
#define NBINS 512                 // 9-bit digits
#define RADIX_BITS 9
#define ROUNDS (TILE / THREADS)   // 16
#define CHUNK (TILE / 4)          // 1024 elements per wave

#define FLAG_PARTIAL 0x40000000u
#define FLAG_PREFIX  0x80000000u
#define FLAG_MASK    0xC0000000u
#define CNT_MASK     0x3FFFFFFFu

// ---------------- Hilbert key (Skilling transpose algorithm, DEPTH=8) --------
__device__ __forceinline__ uint32_t hilbert_code(uint32_t x, uint32_t y, uint32_t z) {
  uint32_t X0 = x & 255u, X1 = y & 255u, X2 = z & 255u;
#pragma unroll
  for (int p = 7; p >= 0; --p) {
    uint32_t low = (1u << p) - 1u;
    uint32_t f0 = (uint32_t)-(int)((X0 >> p) & 1u);
    X0 ^= (low & f0);
    uint32_t f1 = (uint32_t)-(int)((X1 >> p) & 1u);
    uint32_t t1 = ((X0 ^ X1) & low) & ~f1;
    X0 ^= (low & f1) ^ t1;
    X1 ^= t1;
    uint32_t f2 = (uint32_t)-(int)((X2 >> p) & 1u);
    uint32_t t2 = ((X0 ^ X2) & low) & ~f2;
    X0 ^= (low & f2) ^ t2;
    X2 ^= t2;
  }
  uint32_t G = 0;
#pragma unroll
  for (int k = 0; k < 8; ++k) {
    int p = 7 - k;
    G |= ((X0 >> p) & 1u) << (23 - 3 * k);
    G |= ((X1 >> p) & 1u) << (22 - 3 * k);
    G |= ((X2 >> p) & 1u) << (21 - 3 * k);
  }
  G ^= G >> 16; G ^= G >> 8; G ^= G >> 4; G ^= G >> 2; G ^= G >> 1;
  return G & 0xFFFFFFu;
}

// -------- key generation fused with ALL THREE pass histograms ---------------
__global__ __launch_bounds__(THREADS) void genkeys_hist3(
    const int4* __restrict__ coords, const void* __restrict__ ss,
    const int* __restrict__ shifts, uint64_t* __restrict__ pairs,
    int* __restrict__ hist3, int N) {
  __shared__ int lh[3][NBINS];
  int t = threadIdx.x, b = blockIdx.x;
  for (int i = t; i < 3 * NBINS; i += THREADS) ((int*)lh)[i] = 0;

  const int* p32 = (const int*)ss;
  int D, H, W;
  if (p32[1] == 0) { const long long* p64 = (const long long*)ss;
    D = (int)p64[0]; H = (int)p64[1]; W = (int)p64[2]; }
  else { D = p32[0]; H = p32[1]; W = p32[2]; }
  int sflag = shifts[0];
  int sx = sflag ? 15 : 0, sy = sflag ? 15 : 0, sz = sflag ? 4 : 0;
  bool wp2 = (W & (W - 1)) == 0, hp2 = (H & (H - 1)) == 0, dp2 = (D & (D - 1)) == 0;
  __syncthreads();

#pragma unroll
  for (int r = 0; r < ROUNDS; ++r) {
    int idx = b * TILE + r * THREADS + t;
    if (idx < N) {
      int4 c = coords[idx];            // (b, z, y, x)
      uint32_t bb = (uint32_t)c.x;
      int zz = c.y + sz, yy = c.z + sy, xx = c.w + sx;
      uint32_t z = (uint32_t)(dp2 ? (zz & (D - 1)) : (zz % D));
      uint32_t y = (uint32_t)(hp2 ? (yy & (H - 1)) : (yy % H));
      uint32_t x = (uint32_t)(wp2 ? (xx & (W - 1)) : (xx % W));
      uint32_t code = hilbert_code(x, y, z) | (bb << 24);
      pairs[idx] = ((uint64_t)(uint32_t)idx << 32) | code;
      atomicAdd(&lh[0][code & (NBINS - 1)], 1);
      atomicAdd(&lh[1][(code >> 9) & (NBINS - 1)], 1);
      atomicAdd(&lh[2][(code >> 18) & (NBINS - 1)], 1);
    }
  }
  __syncthreads();
  for (int i = t; i < 3 * NBINS; i += THREADS) {
    int v = ((int*)lh)[i];
    if (v) atomicAdd(&hist3[i], v);    // device-scope: correct across XCDs
  }
}

// -------- exclusive scan of each 512-bin histogram (grid = 3) ---------------
__global__ __launch_bounds__(THREADS) void scan3(
    const int* __restrict__ hist3, int* __restrict__ digitBase3) {
  __shared__ int s[NBINS];
  int p = blockIdx.x, t = threadIdx.x;
  const int* h = hist3 + p * NBINS;
  int* o = digitBase3 + p * NBINS;
  int v0 = h[t], v1 = h[t + 256];
  s[t] = v0; s[t + 256] = v1;
  __syncthreads();
  for (int off = 1; off < NBINS; off <<= 1) {
    int a0 = (t >= off) ? s[t - off] : 0;
    int a1 = s[t + 256 - off];
    int b0 = s[t], b1 = s[t + 256];
    __syncthreads();
    s[t] = b0 + a0; s[t + 256] = b1 + a1;
    __syncthreads();
  }
  o[t] = s[t] - v0;
  o[t + 256] = s[t + 256] - v1;
}

// -------- stable scatter: decoupled lookback + LDS-staged writes ------------
// Stability within block: (wave, round, lane) == original index order, since
// wave w owns the contiguous chunk [b*TILE + w*CHUNK, +CHUNK).
template <int SHIFT, bool FINAL>
__global__ __launch_bounds__(THREADS) void scatter_lookback(
    const uint64_t* __restrict__ pairsIn,
    uint64_t* __restrict__ pairsOut, int* __restrict__ valsOut,
    const int* __restrict__ digitBase, uint32_t* __restrict__ status,
    int N, int nblocks) {
  __shared__ uint64_t sbuf[TILE];                  // staging; reused as int scan scratch
  __shared__ unsigned short cnt[4][NBINS];         // per-wave digit counters -> offsets
  __shared__ int digitStart[NBINS];
  __shared__ int adjArr[NBINS];
  int t = threadIdx.x, b = blockIdx.x;
  int wave = t >> 6, lane = t & 63;

  for (int d = t; d < NBINS; d += THREADS) {
    cnt[0][d] = 0; cnt[1][d] = 0; cnt[2][d] = 0; cnt[3][d] = 0;
  }
  __syncthreads();

  uint64_t kvR[ROUNDS];
  int drR[ROUNDS];                                 // digit | rankInChunk<<9, -1 invalid
  uint64_t lt = (1ull << lane) - 1ull;
  int chunk0 = b * TILE + wave * CHUNK;

  // ---- phase A: wave-private stable ranking (no barriers) ----
#pragma unroll
  for (int r = 0; r < ROUNDS; ++r) {
    int idx = chunk0 + r * 64 + lane;
    bool valid = idx < N;
    uint64_t kv = valid ? pairsIn[idx] : 0ull;
    kvR[r] = kv;
    int digit = (int)(((uint32_t)kv >> SHIFT) & (NBINS - 1));
    uint64_t eq = __ballot(valid);
#pragma unroll
    for (int bit = 0; bit < RADIX_BITS; ++bit) {
      uint64_t m = __ballot((digit >> bit) & 1);
      eq &= ((digit >> bit) & 1) ? m : ~m;
    }
    int waveRank = __popcll(eq & lt);
    int cntW = __popcll(eq);
    int prior = cnt[wave][digit];                  // wave-private row: no race
    drR[r] = valid ? (digit | ((prior + waveRank) << RADIX_BITS)) : -1;
    if (valid && waveRank == 0) cnt[wave][digit] = (unsigned short)(prior + cntW);
  }
  __syncthreads();

  // ---- totals + publish + decoupled lookback (thread t owns digits t,t+256) --
  int d0 = t, d1 = t + 256;
  int tot0, tot1, excl0 = 0, excl1 = 0;
  {
    int c0 = cnt[0][d0], c1 = cnt[1][d0], c2 = cnt[2][d0], c3 = cnt[3][d0];
    cnt[0][d0] = 0; cnt[1][d0] = (unsigned short)c0;
    cnt[2][d0] = (unsigned short)(c0 + c1); cnt[3][d0] = (unsigned short)(c0 + c1 + c2);
    tot0 = c0 + c1 + c2 + c3;
    int e0 = cnt[0][d1], e1 = cnt[1][d1], e2 = cnt[2][d1], e3 = cnt[3][d1];
    cnt[0][d1] = 0; cnt[1][d1] = (unsigned short)e0;
    cnt[2][d1] = (unsigned short)(e0 + e1); cnt[3][d1] = (unsigned short)(e0 + e1 + e2);
    tot1 = e0 + e1 + e2 + e3;

    uint32_t f = (b == 0) ? FLAG_PREFIX : FLAG_PARTIAL;
    __hip_atomic_store(&status[(size_t)d0 * nblocks + b], (uint32_t)tot0 | f,
                       __ATOMIC_RELAXED, __HIP_MEMORY_SCOPE_AGENT);
    __hip_atomic_store(&status[(size_t)d1 * nblocks + b], (uint32_t)tot1 | f,
                       __ATOMIC_RELAXED, __HIP_MEMORY_SCOPE_AGENT);
    if (b > 0) {
      for (int p = b - 1;; --p) {
        uint32_t v;
        for (;;) {
          v = __hip_atomic_load(&status[(size_t)d0 * nblocks + p],
                                __ATOMIC_RELAXED, __HIP_MEMORY_SCOPE_AGENT);
          if (v & FLAG_MASK) break;
          __builtin_amdgcn_s_sleep(1);
        }
        excl0 += (int)(v & CNT_MASK);
        if (v & FLAG_PREFIX) break;
      }
      for (int p = b - 1;; --p) {
        uint32_t v;
        for (;;) {
          v = __hip_atomic_load(&status[(size_t)d1 * nblocks + p],
                                __ATOMIC_RELAXED, __HIP_MEMORY_SCOPE_AGENT);
          if (v & FLAG_MASK) break;
          __builtin_amdgcn_s_sleep(1);
        }
        excl1 += (int)(v & CNT_MASK);
        if (v & FLAG_PREFIX) break;
      }
      __hip_atomic_store(&status[(size_t)d0 * nblocks + b],
                         (uint32_t)(tot0 + excl0) | FLAG_PREFIX,
                         __ATOMIC_RELAXED, __HIP_MEMORY_SCOPE_AGENT);
      __hip_atomic_store(&status[(size_t)d1 * nblocks + b],
                         (uint32_t)(tot1 + excl1) | FLAG_PREFIX,
                         __ATOMIC_RELAXED, __HIP_MEMORY_SCOPE_AGENT);
    }
  }

  // ---- in-block exclusive scan of digit totals -> digitStart ----
  int* s = (int*)sbuf;
  s[d0] = tot0; s[d1] = tot1;
  __syncthreads();
  {
    for (int off = 1; off < NBINS; off <<= 1) {
      int a0 = (t >= off) ? s[t - off] : 0;
      int a1 = s[t + 256 - off];
      int b0 = s[t], b1 = s[t + 256];
      __syncthreads();
      s[t] = b0 + a0; s[t + 256] = b1 + a1;
      __syncthreads();
    }
    int ds0 = s[t] - tot0, ds1 = s[t + 256] - tot1;
    digitStart[d0] = ds0;
    digitStart[d1] = ds1;
    adjArr[d0] = digitBase[d0] + excl0 - ds0;
    adjArr[d1] = digitBase[d1] + excl1 - ds1;
  }
  __syncthreads();

  // ---- stage pairs into LDS in digit-sorted order ----
#pragma unroll
  for (int r = 0; r < ROUNDS; ++r) {
    int dr = drR[r];
    if (dr >= 0) {
      int digit = dr & (NBINS - 1);
      int rnk = dr >> RADIX_BITS;
      sbuf[digitStart[digit] + (int)cnt[wave][digit] + rnk] = kvR[r];
    }
  }
  __syncthreads();

  // ---- write out sequentially: runs of a digit are contiguous (avg 64B) ----
  int validCount = min(TILE, N - b * TILE);
#pragma unroll
  for (int j = 0; j < ROUNDS; ++j) {
    int i = j * THREADS + t;
    if (i < validCount) {
      uint64_t kv = sbuf[i];
      int digit = (int)(((uint32_t)kv >> SHIFT) & (NBINS - 1));
      int pos = adjArr[digit] + i;
      if (FINAL) valsOut[pos] = (int)(kv >> 32);
      else pairsOut[pos] = kv;
    }
  }
}

// ---------------- launch ----------------
extern "C" void kernel_launch(void* const* d_in, const int* in_sizes, int n_in,
                              void* d_out, int out_size, void* d_ws, size_t ws_size,
                              hipStream_t stream) {
  const int4* coords = (const int4*)d_in[0];
  const void* ss = d_in[1];
  const int* shifts = (const int*)d_in[2];
  int N = in_sizes[0] / 4;
  int nblocks = (N + TILE - 1) / TILE;

  char* ws = (char*)d_ws;
  size_t off = 0;
  auto alloc = [&](size_t bytes) -> void* {
    void* p = ws + off;
    off += (bytes + 255) & ~(size_t)255;
    return p;
  };
  uint64_t* pairsA = (uint64_t*)alloc((size_t)N * 8);
  uint64_t* pairsB = (uint64_t*)alloc((size_t)N * 8);
  int*      hist3  = (int*)alloc(3 * NBINS * 4);            // contiguous with status
  uint32_t* status = (uint32_t*)alloc((size_t)3 * NBINS * nblocks * 4);
  int*      digitBase3 = (int*)alloc(3 * NBINS * 4);

  uint32_t* status0 = status;
  uint32_t* status1 = status + (size_t)NBINS * nblocks;
  uint32_t* status2 = status + (size_t)2 * NBINS * nblocks;

  // zero hist3 + status (must happen every call: graph replays don't re-poison)
  size_t zbytes = (size_t)3 * NBINS * 4 + 256 /*alloc pad*/;
  zbytes = ((size_t)((char*)status - (char*)hist3)) + (size_t)3 * NBINS * nblocks * 4;
  hipMemsetAsync(hist3, 0, zbytes, stream);

  genkeys_hist3<<<nblocks, THREADS, 0, stream>>>(coords, ss, shifts, pairsA, hist3, N);
  scan3<<<3, THREADS, 0, stream>>>(hist3, digitBase3);

  scatter_lookback<0, false><<<nblocks, THREADS, 0, stream>>>(
      pairsA, pairsB, nullptr, digitBase3, status0, N, nblocks);
  scatter_lookback<9, false><<<nblocks, THREADS, 0, stream>>>(
      pairsB, pairsA, nullptr, digitBase3 + NBINS, status1, N, nblocks);
  scatter_lookback<18, true><<<nblocks, THREADS, 0, stream>>>(
      pairsA, nullptr, (int*)d_out, digitBase3 + 2 * NBINS, status2, N, nblocks);
}

// Round 5
// 90.302 us; speedup vs baseline: 6.0628x; 6.0628x over previous
//
#include <hip/hip_runtime.h>
#include <stdint.h>

// HilbertSerialization: stable argsort of 26-bit Hilbert+batch keys.
// 3 passes x 9-bit LSD radix over fused (val<<32|key) uint64 pairs.
// Structure (reduce-then-scan, R3): genkeys(+hist0) -> [scan_blocks, scatter] x3.
// R5: 512-thread scatter (8 waves, shorter LDS rank chain, 24 waves/CU),
// shuffle-based digit scan (2 barriers), hist matrix transposed to
// [block][digit] so the scatter's hist load is one coalesced 2KB read.

#define THREADS 512
#define TILE 4096                 // elements per block
#define NBINS 512                 // 9-bit digits
#define RADIX_BITS 9
#define ROUNDS (TILE / THREADS)   // 8
#define WAVES (THREADS / 64)      // 8
#define CHUNK (TILE / WAVES)      // 512 elements per wave

// ---------------- Hilbert key (Skilling transpose algorithm, DEPTH=8) --------
__device__ __forceinline__ uint32_t hilbert_code(uint32_t x, uint32_t y, uint32_t z) {
  uint32_t X0 = x & 255u, X1 = y & 255u, X2 = z & 255u;
#pragma unroll
  for (int p = 7; p >= 0; --p) {
    uint32_t low = (1u << p) - 1u;
    uint32_t f0 = (uint32_t)-(int)((X0 >> p) & 1u);
    X0 ^= (low & f0);
    uint32_t f1 = (uint32_t)-(int)((X1 >> p) & 1u);
    uint32_t t1 = ((X0 ^ X1) & low) & ~f1;
    X0 ^= (low & f1) ^ t1;
    X1 ^= t1;
    uint32_t f2 = (uint32_t)-(int)((X2 >> p) & 1u);
    uint32_t t2 = ((X0 ^ X2) & low) & ~f2;
    X0 ^= (low & f2) ^ t2;
    X2 ^= t2;
  }
  uint32_t G = 0;
#pragma unroll
  for (int k = 0; k < 8; ++k) {
    int p = 7 - k;
    G |= ((X0 >> p) & 1u) << (23 - 3 * k);
    G |= ((X1 >> p) & 1u) << (22 - 3 * k);
    G |= ((X2 >> p) & 1u) << (21 - 3 * k);
  }
  G ^= G >> 16; G ^= G >> 8; G ^= G >> 4; G ^= G >> 2; G ^= G >> 1;
  return G & 0xFFFFFFu;
}

// ---------------- key generation fused with pass-0 histogram -----------------
__global__ __launch_bounds__(THREADS) void genkeys_hist(
    const int4* __restrict__ coords, const void* __restrict__ ss,
    const int* __restrict__ shifts, uint64_t* __restrict__ pairs,
    int* __restrict__ hist, int N) {
  __shared__ int lh[NBINS];
  int t = threadIdx.x, b = blockIdx.x;
  if (t < NBINS) lh[t] = 0;

  const int* p32 = (const int*)ss;
  int D, H, W;
  if (p32[1] == 0) { const long long* p64 = (const long long*)ss;
    D = (int)p64[0]; H = (int)p64[1]; W = (int)p64[2]; }
  else { D = p32[0]; H = p32[1]; W = p32[2]; }
  int sflag = shifts[0];
  int sx = sflag ? 15 : 0, sy = sflag ? 15 : 0, sz = sflag ? 4 : 0;
  bool wp2 = (W & (W - 1)) == 0, hp2 = (H & (H - 1)) == 0, dp2 = (D & (D - 1)) == 0;
  __syncthreads();

#pragma unroll
  for (int r = 0; r < ROUNDS; ++r) {
    int idx = b * TILE + r * THREADS + t;
    if (idx < N) {
      int4 c = coords[idx];            // (b, z, y, x)
      uint32_t bb = (uint32_t)c.x;
      int zz = c.y + sz, yy = c.z + sy, xx = c.w + sx;
      uint32_t z = (uint32_t)(dp2 ? (zz & (D - 1)) : (zz % D));
      uint32_t y = (uint32_t)(hp2 ? (yy & (H - 1)) : (yy % H));
      uint32_t x = (uint32_t)(wp2 ? (xx & (W - 1)) : (xx % W));
      uint32_t code = hilbert_code(x, y, z) | (bb << 24);
      pairs[idx] = ((uint64_t)(uint32_t)idx << 32) | code;
      atomicAdd(&lh[code & (NBINS - 1)], 1);
    }
  }
  __syncthreads();
  if (t < NBINS) hist[(size_t)b * NBINS + t] = lh[t];   // [block][digit]: coalesced
}

// ---------------- per-pass histogram (reads key = low word of pair) ---------
template <int SHIFT>
__global__ __launch_bounds__(THREADS) void hist_kernel(
    const uint64_t* __restrict__ pairs, int* __restrict__ hist, int N) {
  __shared__ int lh[NBINS];
  int t = threadIdx.x, b = blockIdx.x;
  if (t < NBINS) lh[t] = 0;
  __syncthreads();
  const uint32_t* keys = (const uint32_t*)pairs;   // low word at 2*idx
#pragma unroll
  for (int r = 0; r < ROUNDS; ++r) {
    int idx = b * TILE + r * THREADS + t;
    if (idx < N) atomicAdd(&lh[(keys[(size_t)idx * 2] >> SHIFT) & (NBINS - 1)], 1);
  }
  __syncthreads();
  if (t < NBINS) hist[(size_t)b * NBINS + t] = lh[t];
}

// ---- per digit, exclusive scan over blocks (in place), total out -----------
// hist layout [block][digit]; strided reads are L2-amortized (matrix = 1 MB).
__global__ __launch_bounds__(256) void scan_blocks(
    int* __restrict__ hist, int* __restrict__ digitTotals, int nblocks) {
  __shared__ int s[512];
  int d = blockIdx.x, t = threadIdx.x;
  int carry = 0;
  for (int start = 0; start < nblocks; start += 512) {
    int i0 = start + t, i1 = start + t + 256;
    int v0 = (i0 < nblocks) ? hist[(size_t)i0 * NBINS + d] : 0;
    int v1 = (i1 < nblocks) ? hist[(size_t)i1 * NBINS + d] : 0;
    s[t] = v0; s[t + 256] = v1;
    __syncthreads();
    for (int off = 1; off < 512; off <<= 1) {
      int a0 = (t >= off) ? s[t - off] : 0;
      int a1 = s[t + 256 - off];
      int b0 = s[t], b1 = s[t + 256];
      __syncthreads();
      s[t] = b0 + a0; s[t + 256] = b1 + a1;
      __syncthreads();
    }
    if (i0 < nblocks) hist[(size_t)i0 * NBINS + d] = carry + s[t] - v0;
    if (i1 < nblocks) hist[(size_t)i1 * NBINS + d] = carry + s[t + 256] - v1;
    int total = s[511];
    __syncthreads();
    carry += total;
  }
  if (t == 0) digitTotals[d] = carry;
}

// ---------------- stable scatter with LDS staging ----------------
// Stability within block: (wave, round, lane) == original index order, since
// wave w owns the contiguous chunk [b*TILE + w*CHUNK, +CHUNK).
template <int SHIFT, bool FINAL>
__global__ __launch_bounds__(THREADS) void scatter_kernel(
    const uint64_t* __restrict__ pairsIn,
    uint64_t* __restrict__ pairsOut, int* __restrict__ valsOut,
    const int* __restrict__ hist, const int* __restrict__ digitTotals,
    int N, int nblocks) {
  __shared__ uint64_t sbuf[TILE];                  // 32 KB staging
  __shared__ unsigned short cnt[WAVES][NBINS];     // 8 KB per-wave digit counts
  __shared__ int digitStart[NBINS];
  __shared__ int adjArr[NBINS];
  __shared__ int2 wtot[WAVES];
  int t = threadIdx.x, b = blockIdx.x;
  int wave = t >> 6, lane = t & 63;

  // prefetch (coalesced: 2 KB each) + init
  int histv = 0, dt = 0;
  if (t < NBINS) {
    histv = hist[(size_t)b * NBINS + t];
    dt = digitTotals[t];
  }
#pragma unroll
  for (int w = 0; w < WAVES; ++w) cnt[w][t] = 0;   // t in [0,512): one bin per thread
  __syncthreads();

  uint64_t kvR[ROUNDS];
  int drR[ROUNDS];                                 // digit | rankInChunk<<9, -1 invalid
  uint64_t lt = (1ull << lane) - 1ull;
  int chunk0 = b * TILE + wave * CHUNK;

  // ---- phase A: wave-private stable ranking (no barriers) ----
#pragma unroll
  for (int r = 0; r < ROUNDS; ++r) {
    int idx = chunk0 + r * 64 + lane;
    bool valid = idx < N;
    uint64_t kv = valid ? pairsIn[idx] : 0ull;
    kvR[r] = kv;
    int digit = (int)(((uint32_t)kv >> SHIFT) & (NBINS - 1));
    uint64_t eq = __ballot(valid);
#pragma unroll
    for (int bit = 0; bit < RADIX_BITS; ++bit) {
      uint64_t m = __ballot((digit >> bit) & 1);
      eq &= ((digit >> bit) & 1) ? m : ~m;
    }
    int waveRank = __popcll(eq & lt);
    int cntW = __popcll(eq);
    int prior = cnt[wave][digit];                  // wave-private row: no race
    drR[r] = valid ? (digit | ((prior + waveRank) << RADIX_BITS)) : -1;
    if (valid && waveRank == 0) cnt[wave][digit] = (unsigned short)(prior + cntW);
  }
  __syncthreads();

  // ---- cross-wave combine: thread t owns bin t (disjoint) ----
  int tot = 0;
  {
#pragma unroll
    for (int w = 0; w < WAVES; ++w) {
      int x = cnt[w][t];
      cnt[w][t] = (unsigned short)tot;             // exclusive wave offset
      tot += x;
    }
  }

  // ---- 512-bin int2 scan via wave shuffles: .x=blockTot, .y=digitTot ----
  {
    int2 v = make_int2(tot, dt);
#pragma unroll
    for (int off = 1; off < 64; off <<= 1) {
      int nx = __shfl_up(v.x, off);
      int ny = __shfl_up(v.y, off);
      if (lane >= off) { v.x += nx; v.y += ny; }
    }
    if (lane == 63) wtot[wave] = v;
    __syncthreads();
    int2 pre = make_int2(0, 0);
    for (int w = 0; w < wave; ++w) { pre.x += wtot[w].x; pre.y += wtot[w].y; }
    int ds = v.x + pre.x - tot;                    // exclusive in-block digit start
    digitStart[t] = ds;
    adjArr[t] = histv + (v.y + pre.y - dt) - ds;   // globalBase - digitStart
  }
  __syncthreads();

  // ---- stage pairs into LDS in digit-sorted order ----
#pragma unroll
  for (int r = 0; r < ROUNDS; ++r) {
    int dr = drR[r];
    if (dr >= 0) {
      int digit = dr & (NBINS - 1);
      int rnk = dr >> RADIX_BITS;
      sbuf[digitStart[digit] + (int)cnt[wave][digit] + rnk] = kvR[r];
    }
  }
  __syncthreads();

  // ---- write out sequentially: runs of a digit are contiguous (avg 64B) ----
  int validCount = min(TILE, N - b * TILE);
#pragma unroll
  for (int j = 0; j < ROUNDS; ++j) {
    int i = j * THREADS + t;
    if (i < validCount) {
      uint64_t kv = sbuf[i];
      int digit = (int)(((uint32_t)kv >> SHIFT) & (NBINS - 1));
      int pos = adjArr[digit] + i;
      if (FINAL) valsOut[pos] = (int)(kv >> 32);
      else pairsOut[pos] = kv;
    }
  }
}

// ---------------- launch ----------------
extern "C" void kernel_launch(void* const* d_in, const int* in_sizes, int n_in,
                              void* d_out, int out_size, void* d_ws, size_t ws_size,
                              hipStream_t stream) {
  const int4* coords = (const int4*)d_in[0];
  const void* ss = d_in[1];
  const int* shifts = (const int*)d_in[2];
  int N = in_sizes[0] / 4;
  int nblocks = (N + TILE - 1) / TILE;

  char* ws = (char*)d_ws;
  size_t off = 0;
  auto alloc = [&](size_t bytes) -> void* {
    void* p = ws + off;
    off += (bytes + 255) & ~(size_t)255;
    return p;
  };
  uint64_t* pairsA = (uint64_t*)alloc((size_t)N * 8);
  uint64_t* pairsB = (uint64_t*)alloc((size_t)N * 8);
  int*      hist   = (int*)alloc((size_t)NBINS * nblocks * 4);
  int*      digitTotals = (int*)alloc(NBINS * 4);

  // pass 0 (bits 0..8): vals implicit (val == idx), fused into genkeys
  genkeys_hist<<<nblocks, THREADS, 0, stream>>>(coords, ss, shifts, pairsA, hist, N);
  scan_blocks<<<NBINS, 256, 0, stream>>>(hist, digitTotals, nblocks);
  scatter_kernel<0, false><<<nblocks, THREADS, 0, stream>>>(
      pairsA, pairsB, nullptr, hist, digitTotals, N, nblocks);

  // pass 1 (bits 9..17)
  hist_kernel<9><<<nblocks, THREADS, 0, stream>>>(pairsB, hist, N);
  scan_blocks<<<NBINS, 256, 0, stream>>>(hist, digitTotals, nblocks);
  scatter_kernel<9, false><<<nblocks, THREADS, 0, stream>>>(
      pairsB, pairsA, nullptr, hist, digitTotals, N, nblocks);

  // pass 2 (bits 18..26): vals land directly in d_out
  hist_kernel<18><<<nblocks, THREADS, 0, stream>>>(pairsA, hist, N);
  scan_blocks<<<NBINS, 256, 0, stream>>>(hist, digitTotals, nblocks);
  scatter_kernel<18, true><<<nblocks, THREADS, 0, stream>>>(
      pairsA, nullptr, (int*)d_out, hist, digitTotals, N, nblocks);
}

// Round 6
// 85.017 us; speedup vs baseline: 6.4398x; 1.0622x over previous
//
#include <hip/hip_runtime.h>
#include <stdint.h>

// HilbertSerialization: stable argsort of 26-bit Hilbert+batch keys.
// 3 passes LSD radix (9,9,8 bits) over fused (val<<32|key) uint64 pairs.
// genkeys(+hist0) -> [scan_blocks, scatter] x3, reduce-then-scan.
// R6: XCD-contiguous tile swizzle; scatter LDS trimmed to 40960B (4 blocks/CU)
// by folding digitStart into cnt rows and reusing cnt as adjArr; final pass
// 256 bins with packed 4B staging; shuffle-based scan_blocks.

#define THREADS 512
#define TILE 4096                 // elements per block
#define ROUNDS (TILE / THREADS)   // 8
#define WAVES (THREADS / 64)      // 8
#define CHUNK (TILE / WAVES)      // 512 elements per wave

// XCD-contiguous bijective tile swizzle: consecutive tiles -> same XCD L2.
__device__ __forceinline__ int tile_of(int bid, int nwg) {
  int q = nwg >> 3, r = nwg & 7;
  int x = bid & 7, k = bid >> 3;
  return x * q + (x < r ? x : r) + k;
}

// ---------------- Hilbert key (Skilling transpose algorithm, DEPTH=8) --------
__device__ __forceinline__ uint32_t hilbert_code(uint32_t x, uint32_t y, uint32_t z) {
  uint32_t X0 = x & 255u, X1 = y & 255u, X2 = z & 255u;
#pragma unroll
  for (int p = 7; p >= 0; --p) {
    uint32_t low = (1u << p) - 1u;
    uint32_t f0 = (uint32_t)-(int)((X0 >> p) & 1u);
    X0 ^= (low & f0);
    uint32_t f1 = (uint32_t)-(int)((X1 >> p) & 1u);
    uint32_t t1 = ((X0 ^ X1) & low) & ~f1;
    X0 ^= (low & f1) ^ t1;
    X1 ^= t1;
    uint32_t f2 = (uint32_t)-(int)((X2 >> p) & 1u);
    uint32_t t2 = ((X0 ^ X2) & low) & ~f2;
    X0 ^= (low & f2) ^ t2;
    X2 ^= t2;
  }
  uint32_t G = 0;
#pragma unroll
  for (int k = 0; k < 8; ++k) {
    int p = 7 - k;
    G |= ((X0 >> p) & 1u) << (23 - 3 * k);
    G |= ((X1 >> p) & 1u) << (22 - 3 * k);
    G |= ((X2 >> p) & 1u) << (21 - 3 * k);
  }
  G ^= G >> 16; G ^= G >> 8; G ^= G >> 4; G ^= G >> 2; G ^= G >> 1;
  return G & 0xFFFFFFu;
}

// ---------------- key generation fused with pass-0 histogram -----------------
__global__ __launch_bounds__(THREADS) void genkeys_hist(
    const int4* __restrict__ coords, const void* __restrict__ ss,
    const int* __restrict__ shifts, uint64_t* __restrict__ pairs,
    int* __restrict__ hist, int N) {
  __shared__ int lh[512];
  int t = threadIdx.x, b = tile_of(blockIdx.x, gridDim.x);
  lh[t] = 0;

  const int* p32 = (const int*)ss;
  int D, H, W;
  if (p32[1] == 0) { const long long* p64 = (const long long*)ss;
    D = (int)p64[0]; H = (int)p64[1]; W = (int)p64[2]; }
  else { D = p32[0]; H = p32[1]; W = p32[2]; }
  int sflag = shifts[0];
  int sx = sflag ? 15 : 0, sy = sflag ? 15 : 0, sz = sflag ? 4 : 0;
  bool wp2 = (W & (W - 1)) == 0, hp2 = (H & (H - 1)) == 0, dp2 = (D & (D - 1)) == 0;
  __syncthreads();

#pragma unroll
  for (int r = 0; r < ROUNDS; ++r) {
    int idx = b * TILE + r * THREADS + t;
    if (idx < N) {
      int4 c = coords[idx];            // (b, z, y, x)
      uint32_t bb = (uint32_t)c.x;
      int zz = c.y + sz, yy = c.z + sy, xx = c.w + sx;
      uint32_t z = (uint32_t)(dp2 ? (zz & (D - 1)) : (zz % D));
      uint32_t y = (uint32_t)(hp2 ? (yy & (H - 1)) : (yy % H));
      uint32_t x = (uint32_t)(wp2 ? (xx & (W - 1)) : (xx % W));
      uint32_t code = hilbert_code(x, y, z) | (bb << 24);
      pairs[idx] = ((uint64_t)(uint32_t)idx << 32) | code;
      atomicAdd(&lh[code & 511u], 1);
    }
  }
  __syncthreads();
  hist[(size_t)b * 512 + t] = lh[t];   // [block][digit]: coalesced
}

// ---------------- per-pass histogram (reads key = low word of pair) ---------
template <int SHIFT, int NB>
__global__ __launch_bounds__(THREADS) void hist_kernel(
    const uint64_t* __restrict__ pairs, int* __restrict__ hist, int N) {
  __shared__ int lh[NB];
  int t = threadIdx.x, b = tile_of(blockIdx.x, gridDim.x);
  if (t < NB) lh[t] = 0;
  __syncthreads();
  const uint32_t* keys = (const uint32_t*)pairs;   // low word at 2*idx
#pragma unroll
  for (int r = 0; r < ROUNDS; ++r) {
    int idx = b * TILE + r * THREADS + t;
    if (idx < N) atomicAdd(&lh[(keys[(size_t)idx * 2] >> SHIFT) & (NB - 1)], 1);
  }
  __syncthreads();
  if (t < NB) hist[(size_t)b * NB + t] = lh[t];
}

// ---- per digit: exclusive scan over blocks (in place), total out -----------
// hist layout [block][digit]; shuffle scan, 2 barriers per 512-chunk.
__global__ __launch_bounds__(512) void scan_blocks(
    int* __restrict__ hist, int* __restrict__ digitTotals, int nblocks, int nbins) {
  __shared__ int wsum[8];
  int d = blockIdx.x, t = threadIdx.x, wave = t >> 6, lane = t & 63;
  int carry = 0;
  for (int start = 0; start < nblocks; start += 512) {
    int i = start + t;
    int vv = (i < nblocks) ? hist[(size_t)i * nbins + d] : 0;
    int x = vv;
#pragma unroll
    for (int off = 1; off < 64; off <<= 1) {
      int n = __shfl_up(x, off);
      if (lane >= off) x += n;
    }
    if (lane == 63) wsum[wave] = x;
    __syncthreads();
    int pre = 0;
    for (int w = 0; w < wave; ++w) pre += wsum[w];
    if (i < nblocks) hist[(size_t)i * nbins + d] = carry + pre + x - vv;
    int tot = 0;
    for (int w = 0; w < 8; ++w) tot += wsum[w];
    __syncthreads();
    carry += tot;
  }
  if (t == 0) digitTotals[d] = carry;
}

// ---------------- stable scatter with LDS staging ----------------
// Stability within block: (wave, round, lane) == original index order.
// LDS budget (middle pass): sbuf 32768 + cnt 8192 = 40960 B -> 4 blocks/CU.
template <int SHIFT, int NB, bool FINAL>
__global__ __launch_bounds__(THREADS) void scatter_kernel(
    const uint64_t* __restrict__ pairsIn,
    uint64_t* __restrict__ pairsOut, int* __restrict__ valsOut,
    const int* __restrict__ hist, const int* __restrict__ digitTotals,
    int N) {
  constexpr int RB = (NB == 512) ? 9 : 8;
  __shared__ uint64_t sbuf[FINAL ? TILE / 2 : TILE];   // staging (+scan scratch)
  __shared__ __align__(16) unsigned short cnt[WAVES][NB];
  int t = threadIdx.x, b = tile_of(blockIdx.x, gridDim.x);
  int wave = t >> 6, lane = t & 63;

  int histv = 0, dt = 0;
  if (t < NB) {
    histv = hist[(size_t)b * NB + t];   // coalesced 2KB row
    dt = digitTotals[t];
  }
  for (int i = t; i < WAVES * NB; i += THREADS) ((unsigned short*)cnt)[i] = 0;
  __syncthreads();

  uint64_t kvR[ROUNDS];
  int drR[ROUNDS];                      // digit | rankInChunk<<RB, -1 invalid
  uint64_t ltm = (1ull << lane) - 1ull;
  int chunk0 = b * TILE + wave * CHUNK;

  // ---- phase A: wave-private stable ranking (no barriers) ----
#pragma unroll
  for (int r = 0; r < ROUNDS; ++r) {
    int idx = chunk0 + r * 64 + lane;
    bool valid = idx < N;
    uint64_t kv = valid ? pairsIn[idx] : 0ull;
    kvR[r] = kv;
    int digit = (int)(((uint32_t)kv >> SHIFT) & (NB - 1));
    uint64_t eq = __ballot(valid);
#pragma unroll
    for (int bit = 0; bit < RB; ++bit) {
      uint64_t m = __ballot((digit >> bit) & 1);
      eq &= ((digit >> bit) & 1) ? m : ~m;
    }
    int waveRank = __popcll(eq & ltm);
    int cntW = __popcll(eq);
    int prior = cnt[wave][digit];       // wave-private row: no race
    drR[r] = valid ? (digit | ((prior + waveRank) << RB)) : -1;
    if (valid && waveRank == 0) cnt[wave][digit] = (unsigned short)(prior + cntW);
  }
  __syncthreads();

  // ---- bin totals + int2 shuffle scan (scratch = dead sbuf) ----
  int2* wt = (int2*)sbuf;
  int tot = 0, adjv = 0;
  int2 v = make_int2(0, 0);
  if (t < NB) {
#pragma unroll
    for (int w = 0; w < WAVES; ++w) tot += cnt[w][t];
    v = make_int2(tot, dt);
#pragma unroll
    for (int off = 1; off < 64; off <<= 1) {
      int nx = __shfl_up(v.x, off), ny = __shfl_up(v.y, off);
      if (lane >= off) { v.x += nx; v.y += ny; }
    }
    if (lane == 63) wt[wave] = v;
  }
  __syncthreads();
  if (t < NB) {
    int2 pre = make_int2(0, 0);
    for (int w = 0; w < wave; ++w) { pre.x += wt[w].x; pre.y += wt[w].y; }
    int ds = pre.x + v.x - tot;         // exclusive in-block digit start
    adjv = histv + (pre.y + v.y - dt) - ds;   // globalBase - digitStart
    int run = ds;                        // fold ds into cnt rows: slot base
#pragma unroll
    for (int w = 0; w < WAVES; ++w) {
      int x = cnt[w][t];
      cnt[w][t] = (unsigned short)run;
      run += x;
    }
  }
  __syncthreads();

  // ---- stage into LDS in digit-sorted order ----
#pragma unroll
  for (int r = 0; r < ROUNDS; ++r) {
    int dr = drR[r];
    if (dr >= 0) {
      int digit = dr & (NB - 1);
      int rnk = dr >> RB;
      int slot = (int)cnt[wave][digit] + rnk;
      if (FINAL)
        ((uint32_t*)sbuf)[slot] = ((uint32_t)digit << 23) | (uint32_t)(kvR[r] >> 32);
      else
        sbuf[slot] = kvR[r];
    }
  }
  __syncthreads();

  // ---- cnt is dead: reuse as adjArr ----
  int* adjArr = (int*)cnt;
  if (t < NB) adjArr[t] = adjv;
  __syncthreads();

  // ---- write out sequentially: digit runs are contiguous ----
  int validCount = min(TILE, N - b * TILE);
#pragma unroll
  for (int j = 0; j < ROUNDS; ++j) {
    int i = j * THREADS + t;
    if (i < validCount) {
      if (FINAL) {
        uint32_t pk = ((uint32_t*)sbuf)[i];
        int digit = (int)(pk >> 23);
        valsOut[adjArr[digit] + i] = (int)(pk & 0x7FFFFFu);
      } else {
        uint64_t kv = sbuf[i];
        int digit = (int)(((uint32_t)kv >> SHIFT) & (NB - 1));
        pairsOut[adjArr[digit] + i] = kv;
      }
    }
  }
}

// ---------------- launch ----------------
extern "C" void kernel_launch(void* const* d_in, const int* in_sizes, int n_in,
                              void* d_out, int out_size, void* d_ws, size_t ws_size,
                              hipStream_t stream) {
  const int4* coords = (const int4*)d_in[0];
  const void* ss = d_in[1];
  const int* shifts = (const int*)d_in[2];
  int N = in_sizes[0] / 4;
  int nblocks = (N + TILE - 1) / TILE;

  char* ws = (char*)d_ws;
  size_t off = 0;
  auto alloc = [&](size_t bytes) -> void* {
    void* p = ws + off;
    off += (bytes + 255) & ~(size_t)255;
    return p;
  };
  uint64_t* pairsA = (uint64_t*)alloc((size_t)N * 8);
  uint64_t* pairsB = (uint64_t*)alloc((size_t)N * 8);
  int*      hist   = (int*)alloc((size_t)512 * nblocks * 4);
  int*      digitTotals = (int*)alloc(512 * 4);

  // pass 0 (bits 0..8, 512 bins): vals implicit (val == idx), fused in genkeys
  genkeys_hist<<<nblocks, THREADS, 0, stream>>>(coords, ss, shifts, pairsA, hist, N);
  scan_blocks<<<512, 512, 0, stream>>>(hist, digitTotals, nblocks, 512);
  scatter_kernel<0, 512, false><<<nblocks, THREADS, 0, stream>>>(
      pairsA, pairsB, nullptr, hist, digitTotals, N);

  // pass 1 (bits 9..17, 512 bins)
  hist_kernel<9, 512><<<nblocks, THREADS, 0, stream>>>(pairsB, hist, N);
  scan_blocks<<<512, 512, 0, stream>>>(hist, digitTotals, nblocks, 512);
  scatter_kernel<9, 512, false><<<nblocks, THREADS, 0, stream>>>(
      pairsB, pairsA, nullptr, hist, digitTotals, N);

  // pass 2 (bits 18..25, 256 bins): vals land directly in d_out
  hist_kernel<18, 256><<<nblocks, THREADS, 0, stream>>>(pairsA, hist, N);
  scan_blocks<<<256, 512, 0, stream>>>(hist, digitTotals, nblocks, 256);
  scatter_kernel<18, 256, true><<<nblocks, THREADS, 0, stream>>>(
      pairsA, nullptr, (int*)d_out, hist, digitTotals, N);
}

// Round 7
// 82.603 us; speedup vs baseline: 6.6280x; 1.0292x over previous
//
#include <hip/hip_runtime.h>
#include <stdint.h>

// HilbertSerialization: stable argsort of 26-bit Hilbert+batch keys.
// 3 passes LSD radix (9,9,8 bits), reduce-then-scan.
// R7 dataflow: genkeys -> keys0 (4B) -> scatter0 -> keys1+vals1 (SoA 4B+4B)
//   -> scatter1 -> packed (digit2<<22|idx, 4B) -> scatter2 -> d_out (4B).
// Payload shrinks every pass; hists read narrow 4B streams (no 8B-line fetch).

#define THREADS 512
#define TILE 4096                 // elements per block
#define ROUNDS (TILE / THREADS)   // 8
#define WAVES (THREADS / 64)      // 8
#define CHUNK (TILE / WAVES)      // 512 elements per wave
#define IDX_BITS 22
#define IDX_MASK 0x3FFFFFu

// XCD-contiguous bijective tile swizzle: consecutive tiles -> same XCD L2.
__device__ __forceinline__ int tile_of(int bid, int nwg) {
  int q = nwg >> 3, r = nwg & 7;
  int x = bid & 7, k = bid >> 3;
  return x * q + (x < r ? x : r) + k;
}

// ---------------- Hilbert key (Skilling transpose algorithm, DEPTH=8) --------
__device__ __forceinline__ uint32_t hilbert_code(uint32_t x, uint32_t y, uint32_t z) {
  uint32_t X0 = x & 255u, X1 = y & 255u, X2 = z & 255u;
#pragma unroll
  for (int p = 7; p >= 0; --p) {
    uint32_t low = (1u << p) - 1u;
    uint32_t f0 = (uint32_t)-(int)((X0 >> p) & 1u);
    X0 ^= (low & f0);
    uint32_t f1 = (uint32_t)-(int)((X1 >> p) & 1u);
    uint32_t t1 = ((X0 ^ X1) & low) & ~f1;
    X0 ^= (low & f1) ^ t1;
    X1 ^= t1;
    uint32_t f2 = (uint32_t)-(int)((X2 >> p) & 1u);
    uint32_t t2 = ((X0 ^ X2) & low) & ~f2;
    X0 ^= (low & f2) ^ t2;
    X2 ^= t2;
  }
  uint32_t G = 0;
#pragma unroll
  for (int k = 0; k < 8; ++k) {
    int p = 7 - k;
    G |= ((X0 >> p) & 1u) << (23 - 3 * k);
    G |= ((X1 >> p) & 1u) << (22 - 3 * k);
    G |= ((X2 >> p) & 1u) << (21 - 3 * k);
  }
  G ^= G >> 16; G ^= G >> 8; G ^= G >> 4; G ^= G >> 2; G ^= G >> 1;
  return G & 0xFFFFFFu;
}

// ---------------- key generation fused with pass-0 histogram -----------------
__global__ __launch_bounds__(THREADS) void genkeys_hist(
    const int4* __restrict__ coords, const void* __restrict__ ss,
    const int* __restrict__ shifts, uint32_t* __restrict__ keys0,
    int* __restrict__ hist, int N) {
  __shared__ int lh[512];
  int t = threadIdx.x, b = tile_of(blockIdx.x, gridDim.x);
  lh[t] = 0;

  const int* p32 = (const int*)ss;
  int D, H, W;
  if (p32[1] == 0) { const long long* p64 = (const long long*)ss;
    D = (int)p64[0]; H = (int)p64[1]; W = (int)p64[2]; }
  else { D = p32[0]; H = p32[1]; W = p32[2]; }
  int sflag = shifts[0];
  int sx = sflag ? 15 : 0, sy = sflag ? 15 : 0, sz = sflag ? 4 : 0;
  bool wp2 = (W & (W - 1)) == 0, hp2 = (H & (H - 1)) == 0, dp2 = (D & (D - 1)) == 0;
  __syncthreads();

#pragma unroll
  for (int r = 0; r < ROUNDS; ++r) {
    int idx = b * TILE + r * THREADS + t;
    if (idx < N) {
      int4 c = coords[idx];            // (b, z, y, x)
      uint32_t bb = (uint32_t)c.x;
      int zz = c.y + sz, yy = c.z + sy, xx = c.w + sx;
      uint32_t z = (uint32_t)(dp2 ? (zz & (D - 1)) : (zz % D));
      uint32_t y = (uint32_t)(hp2 ? (yy & (H - 1)) : (yy % H));
      uint32_t x = (uint32_t)(wp2 ? (xx & (W - 1)) : (xx % W));
      uint32_t code = hilbert_code(x, y, z) | (bb << 24);
      keys0[idx] = code;
      atomicAdd(&lh[code & 511u], 1);
    }
  }
  __syncthreads();
  hist[(size_t)b * 512 + t] = lh[t];   // [block][digit]: coalesced
}

// ---------------- per-pass histogram over a 4B stream ----------------
template <int SHIFT, int NB>
__global__ __launch_bounds__(THREADS) void hist_kernel(
    const uint32_t* __restrict__ keys, int* __restrict__ hist, int N) {
  __shared__ int lh[NB];
  int t = threadIdx.x, b = tile_of(blockIdx.x, gridDim.x);
  if (t < NB) lh[t] = 0;
  __syncthreads();
#pragma unroll
  for (int r = 0; r < ROUNDS; ++r) {
    int idx = b * TILE + r * THREADS + t;
    if (idx < N) atomicAdd(&lh[(keys[idx] >> SHIFT) & (NB - 1)], 1);
  }
  __syncthreads();
  if (t < NB) hist[(size_t)b * NB + t] = lh[t];
}

// ---- per digit: exclusive scan over blocks (in place), total out -----------
__global__ __launch_bounds__(512) void scan_blocks(
    int* __restrict__ hist, int* __restrict__ digitTotals, int nblocks, int nbins) {
  __shared__ int wsum[8];
  int d = blockIdx.x, t = threadIdx.x, wave = t >> 6, lane = t & 63;
  int carry = 0;
  for (int start = 0; start < nblocks; start += 512) {
    int i = start + t;
    int vv = (i < nblocks) ? hist[(size_t)i * nbins + d] : 0;
    int x = vv;
#pragma unroll
    for (int off = 1; off < 64; off <<= 1) {
      int n = __shfl_up(x, off);
      if (lane >= off) x += n;
    }
    if (lane == 63) wsum[wave] = x;
    __syncthreads();
    int pre = 0;
    for (int w = 0; w < wave; ++w) pre += wsum[w];
    if (i < nblocks) hist[(size_t)i * nbins + d] = carry + pre + x - vv;
    int tot = 0;
    for (int w = 0; w < 8; ++w) tot += wsum[w];
    __syncthreads();
    carry += tot;
  }
  if (t == 0) digitTotals[d] = carry;
}

// ---------------- stable scatter with LDS staging ----------------
// MODE 0: in keys0 (digit bits 0..8), val=idx implicit -> out keys1[], vals1[]
// MODE 1: in keys1+vals1 (digit bits 9..17)           -> out packed (d2<<22|idx)
// MODE 2: in packed (digit bits 22..29)               -> out final vals
// Stability within block: (wave, round, lane) == original index order.
template <int MODE>
__global__ __launch_bounds__(THREADS) void scatter_kernel(
    const uint32_t* __restrict__ in0, const uint32_t* __restrict__ in1,
    uint32_t* __restrict__ out0, uint32_t* __restrict__ out1,
    const int* __restrict__ hist, const int* __restrict__ digitTotals, int N) {
  constexpr int NB = (MODE == 2) ? 256 : 512;
  constexpr int RB = (MODE == 2) ? 8 : 9;
  constexpr int SHIFT = (MODE == 0) ? 0 : (MODE == 1) ? 9 : 22;
  __shared__ uint64_t sbuf[(MODE == 2) ? TILE / 2 : TILE];  // 16/32 KB staging
  __shared__ __align__(16) unsigned short cnt[WAVES][NB];   // 4/8 KB
  int t = threadIdx.x, b = tile_of(blockIdx.x, gridDim.x);
  int wave = t >> 6, lane = t & 63;

  int histv = 0, dt = 0;
  if (t < NB) {
    histv = hist[(size_t)b * NB + t];   // coalesced row
    dt = digitTotals[t];
  }
  for (int i = t; i < WAVES * NB; i += THREADS) ((unsigned short*)cnt)[i] = 0;
  __syncthreads();

  uint64_t kvR[ROUNDS];                 // MODE 2 uses low 32 only
  int drR[ROUNDS];                      // digit | rankInChunk<<RB, -1 invalid
  uint64_t ltm = (1ull << lane) - 1ull;
  int chunk0 = b * TILE + wave * CHUNK;

  // ---- phase A: wave-private stable ranking (no barriers) ----
#pragma unroll
  for (int r = 0; r < ROUNDS; ++r) {
    int idx = chunk0 + r * 64 + lane;
    bool valid = idx < N;
    uint32_t a = valid ? in0[idx] : 0u;
    uint64_t kv;
    if (MODE == 0)      kv = ((uint64_t)(uint32_t)idx << 32) | a;
    else if (MODE == 1) kv = ((uint64_t)(valid ? in1[idx] : 0u) << 32) | a;
    else                kv = a;
    kvR[r] = kv;
    int digit = (int)((a >> SHIFT) & (NB - 1));
    uint64_t eq = __ballot(valid);
#pragma unroll
    for (int bit = 0; bit < RB; ++bit) {
      uint64_t m = __ballot((digit >> bit) & 1);
      eq &= ((digit >> bit) & 1) ? m : ~m;
    }
    int waveRank = __popcll(eq & ltm);
    int cntW = __popcll(eq);
    int prior = cnt[wave][digit];       // wave-private row: no race
    drR[r] = valid ? (digit | ((prior + waveRank) << RB)) : -1;
    if (valid && waveRank == 0) cnt[wave][digit] = (unsigned short)(prior + cntW);
  }
  __syncthreads();

  // ---- bin totals + int2 shuffle scan (scratch = dead sbuf) ----
  int2* wt = (int2*)sbuf;
  int tot = 0, adjv = 0;
  int2 v = make_int2(0, 0);
  if (t < NB) {
#pragma unroll
    for (int w = 0; w < WAVES; ++w) tot += cnt[w][t];
    v = make_int2(tot, dt);
#pragma unroll
    for (int off = 1; off < 64; off <<= 1) {
      int nx = __shfl_up(v.x, off), ny = __shfl_up(v.y, off);
      if (lane >= off) { v.x += nx; v.y += ny; }
    }
    if (lane == 63) wt[wave] = v;
  }
  __syncthreads();
  if (t < NB) {
    int2 pre = make_int2(0, 0);
    for (int w = 0; w < wave; ++w) { pre.x += wt[w].x; pre.y += wt[w].y; }
    int ds = pre.x + v.x - tot;         // exclusive in-block digit start
    adjv = histv + (pre.y + v.y - dt) - ds;   // globalBase - digitStart
    int run = ds;                        // fold ds into cnt rows: slot base
#pragma unroll
    for (int w = 0; w < WAVES; ++w) {
      int x = cnt[w][t];
      cnt[w][t] = (unsigned short)run;
      run += x;
    }
  }
  __syncthreads();

  // ---- stage into LDS in digit-sorted order ----
#pragma unroll
  for (int r = 0; r < ROUNDS; ++r) {
    int dr = drR[r];
    if (dr >= 0) {
      int digit = dr & (NB - 1);
      int rnk = dr >> RB;
      int slot = (int)cnt[wave][digit] + rnk;
      if (MODE == 2) ((uint32_t*)sbuf)[slot] = (uint32_t)kvR[r];
      else           sbuf[slot] = kvR[r];
    }
  }
  __syncthreads();

  // ---- cnt is dead: reuse as adjArr ----
  int* adjArr = (int*)cnt;
  if (t < NB) adjArr[t] = adjv;
  __syncthreads();

  // ---- write out sequentially: digit runs are contiguous ----
  int validCount = min(TILE, N - b * TILE);
#pragma unroll
  for (int j = 0; j < ROUNDS; ++j) {
    int i = j * THREADS + t;
    if (i < validCount) {
      if (MODE == 0) {
        uint64_t kv = sbuf[i];
        uint32_t key = (uint32_t)kv;
        int pos = adjArr[key & 511u] + i;
        out0[pos] = key;
        out1[pos] = (uint32_t)(kv >> 32);
      } else if (MODE == 1) {
        uint64_t kv = sbuf[i];
        uint32_t key = (uint32_t)kv, idxv = (uint32_t)(kv >> 32);
        int pos = adjArr[(key >> 9) & 511u] + i;
        out0[pos] = ((key >> 18) << IDX_BITS) | idxv;   // digit2<<22 | idx
      } else {
        uint32_t p = ((uint32_t*)sbuf)[i];
        int pos = adjArr[(p >> IDX_BITS) & 255u] + i;
        out0[pos] = p & IDX_MASK;
      }
    }
  }
}

// ---------------- launch ----------------
extern "C" void kernel_launch(void* const* d_in, const int* in_sizes, int n_in,
                              void* d_out, int out_size, void* d_ws, size_t ws_size,
                              hipStream_t stream) {
  const int4* coords = (const int4*)d_in[0];
  const void* ss = d_in[1];
  const int* shifts = (const int*)d_in[2];
  int N = in_sizes[0] / 4;
  int nblocks = (N + TILE - 1) / TILE;

  char* ws = (char*)d_ws;
  size_t off = 0;
  auto alloc = [&](size_t bytes) -> void* {
    void* p = ws + off;
    off += (bytes + 255) & ~(size_t)255;
    return p;
  };
  uint32_t* keys0 = (uint32_t*)alloc((size_t)N * 4);
  uint32_t* keys1 = (uint32_t*)alloc((size_t)N * 4);
  uint32_t* vals1 = (uint32_t*)alloc((size_t)N * 4);
  uint32_t* packd = (uint32_t*)alloc((size_t)N * 4);
  int*      hist  = (int*)alloc((size_t)512 * nblocks * 4);
  int*      digitTotals = (int*)alloc(512 * 4);

  // pass 0 (bits 0..8, 512 bins): keys only; vals implicit (val == idx)
  genkeys_hist<<<nblocks, THREADS, 0, stream>>>(coords, ss, shifts, keys0, hist, N);
  scan_blocks<<<512, 512, 0, stream>>>(hist, digitTotals, nblocks, 512);
  scatter_kernel<0><<<nblocks, THREADS, 0, stream>>>(
      keys0, nullptr, keys1, vals1, hist, digitTotals, N);

  // pass 1 (bits 9..17, 512 bins): emits packed (digit2<<22 | idx)
  hist_kernel<9, 512><<<nblocks, THREADS, 0, stream>>>(keys1, hist, N);
  scan_blocks<<<512, 512, 0, stream>>>(hist, digitTotals, nblocks, 512);
  scatter_kernel<1><<<nblocks, THREADS, 0, stream>>>(
      keys1, vals1, packd, nullptr, hist, digitTotals, N);

  // pass 2 (packed bits 22..29, 256 bins): vals land directly in d_out
  hist_kernel<22, 256><<<nblocks, THREADS, 0, stream>>>(packd, hist, N);
  scan_blocks<<<256, 512, 0, stream>>>(hist, digitTotals, nblocks, 256);
  scatter_kernel<2><<<nblocks, THREADS, 0, stream>>>(
      packd, nullptr, (uint32_t*)d_out, nullptr, hist, digitTotals, N);
}